// Round 8
// baseline (381.491 us; speedup 1.0000x reference)
//
#include <hip/hip_runtime.h>
#include <math.h>

#define NODES 100000
#define EDGES 1250000
#define HD 64
#define NFD 16
#define CHUNK 1024
#define NCHUNK ((NODES + CHUNK - 1) / CHUNK)
#define BN_INV 0.9999950000374996f  // 1/sqrt(1+1e-5)
#define LP 65    // LDS row pitch: 65 % 32 == 1 -> 2-way bank aliasing (free)
#define BK 1024  // nodes per dst-bucket for the two-level scatter
#define NBKT ((NODES + BK - 1) / BK)  // 98

// ---------------- graph build ----------------

__global__ void k_hist(const int* __restrict__ ei, int* __restrict__ deg) {
  int e = blockIdx.x * blockDim.x + threadIdx.x;
  if (e < EDGES) atomicAdd(&deg[ei[EDGES + e]], 1);
}

__global__ void k_scan1(const int* __restrict__ deg, int* __restrict__ part) {
  __shared__ int lds[256];
  int t = threadIdx.x, b = blockIdx.x;
  int base = b * CHUNK + t * 4;
  int s = 0;
#pragma unroll
  for (int m = 0; m < 4; m++) { int i = base + m; if (i < NODES) s += deg[i]; }
  lds[t] = s; __syncthreads();
  for (int off = 128; off > 0; off >>= 1) {
    if (t < off) lds[t] += lds[t + off];
    __syncthreads();
  }
  if (t == 0) part[b] = lds[0];
}

__global__ void k_scan2(int* __restrict__ part) {
  if (threadIdx.x == 0 && blockIdx.x == 0) {
    int run = 0;
    for (int c = 0; c < NCHUNK; c++) { int v = part[c]; part[c] = run; run += v; }
  }
}

__global__ void k_scan3(const int* __restrict__ deg, const int* __restrict__ part,
                        int* __restrict__ rowptr, int* __restrict__ cur,
                        float* __restrict__ dis) {
  __shared__ int lds[256];
  int t = threadIdx.x, b = blockIdx.x;
  int base = b * CHUNK + t * 4;
  int dl[4]; int s = 0;
#pragma unroll
  for (int m = 0; m < 4; m++) { int i = base + m; dl[m] = (i < NODES) ? deg[i] : 0; s += dl[m]; }
  lds[t] = s; __syncthreads();
  for (int off = 1; off < 256; off <<= 1) {
    int add = (t >= off) ? lds[t - off] : 0;
    __syncthreads();
    lds[t] += add;
    __syncthreads();
  }
  int run = part[b] + lds[t] - s;  // exclusive prefix for this thread
#pragma unroll
  for (int m = 0; m < 4; m++) {
    int i = base + m;
    if (i < NODES) {
      rowptr[i] = run; cur[i] = run;
      dis[i] = 1.0f / sqrtf((float)(dl[m] + 1));  // GCN: indeg + self-loop
    }
    run += dl[m];
  }
  if (b == 0 && t == 0) rowptr[NODES] = EDGES;
}

// bucket cursors = rowptr at bucket boundaries (reuses dead `part` buffer)
__global__ void k_binit(const int* __restrict__ rowptr, int* __restrict__ gcur) {
  int b = threadIdx.x;
  if (b < NBKT) gcur[b] = rowptr[min(b * BK, NODES)];
}

// pass A: per-edge attention coeff + coarse bucket scatter (coalesced runs).
// 2048 edges/block; block-local LDS hist gives intra-block rank; one global
// atomicAdd per (block,bucket); writes land as ~21-entry contiguous runs.
__global__ __launch_bounds__(256) void k_bucket(
    const int* __restrict__ ei, const float* __restrict__ ea,
    const float* __restrict__ cvec, const float* __restrict__ dvec,
    const float* __restrict__ Wa, const float* __restrict__ ba,
    int* __restrict__ gcur, float4* __restrict__ tmp) {
  __shared__ int lhist[NBKT], lbase[NBKT];
  int t = threadIdx.x;
  for (int i = t; i < NBKT; i += 256) lhist[i] = 0;
  __syncthreads();
  float wa0 = Wa[128], wa1 = Wa[129], wa2 = Wa[130], bb = ba[0];
  int base = blockIdx.x * 2048;
  int dl[8], sl[8], rl[8];
  float al[8];
#pragma unroll
  for (int i = 0; i < 8; i++) {
    int e = base + i * 256 + t;
    bool v = e < EDGES;
    int ec = v ? e : EDGES - 1;
    int s = ei[ec], d = ei[EDGES + ec];
    float alin = cvec[d] + dvec[s] + ea[3 * ec] * wa0 + ea[3 * ec + 1] * wa1 +
                 ea[3 * ec + 2] * wa2 + bb;
    float lr = alin >= 0.f ? alin : 0.01f * alin;
    al[i] = 1.f / (1.f + expf(-lr));
    dl[i] = d; sl[i] = s;
    rl[i] = v ? atomicAdd(&lhist[d >> 10], 1) : -1;
  }
  __syncthreads();
  for (int i = t; i < NBKT; i += 256) lbase[i] = atomicAdd(&gcur[i], lhist[i]);
  __syncthreads();
#pragma unroll
  for (int i = 0; i < 8; i++) {
    if (rl[i] >= 0) {
      float4 v;
      v.x = __int_as_float(dl[i]); v.y = __int_as_float(sl[i]); v.z = al[i]; v.w = 0.f;
      tmp[lbase[dl[i] >> 10] + rl[i]] = v;
    }
  }
}

// pass B: one block OWNS one bucket -> fine scatter confined to a ~200KB sa
// window resident in a single XCD's L2 -> writebacks fully merged.
__global__ __launch_bounds__(512) void k_fine(
    const float4* __restrict__ tmp, const int* __restrict__ rowptr,
    int* __restrict__ cur, float2* __restrict__ sa) {
  int b = blockIdx.x;
  int lo = rowptr[b * BK];
  int hi = rowptr[min((b + 1) * BK, NODES)];
  for (int p = lo + (int)threadIdx.x; p < hi; p += 512) {
    float4 v = tmp[p];
    int d = __float_as_int(v.x);
    int q = atomicAdd(&cur[d], 1);
    sa[q] = make_float2(v.y, v.z);
  }
}

// ---------------- tiled node GEMMs ----------------
// 64 nodes/block x 4 col-chunk waves. cc forced to SGPR via readfirstlane ->
// all weight/bias loads scalarize to s_load (constant cache, zero VMEM issue).

__global__ __launch_bounds__(256) void k_lin0(
    const float* __restrict__ x,
    const float* __restrict__ Wn, const float* __restrict__ bn,
    const float* __restrict__ Wl, const float* __restrict__ bl,
    const float* __restrict__ Wa,
    float* __restrict__ hA, float* __restrict__ hB,
    float* __restrict__ cvec, float* __restrict__ dvec) {
  __shared__ float sh[64 * LP];
  __shared__ float sc[4][64], sd[4][64];
  int slot = threadIdx.x & 63;
  int cc = __builtin_amdgcn_readfirstlane(threadIdx.x >> 6);
  int c0 = cc * 16;
  int n0 = blockIdx.x * 64 + slot;
  bool valid = n0 < NODES;
  int n = valid ? n0 : NODES - 1;
  // stage 1 (K=16)
  const float4* xr = (const float4*)(x + (size_t)n * NFD);
  float acc[16];
#pragma unroll
  for (int j = 0; j < 16; j++) acc[j] = bn[c0 + j];
#pragma unroll
  for (int q = 0; q < 4; q++) {
    float4 xa = xr[q];
    float xs[4] = {xa.x, xa.y, xa.z, xa.w};
#pragma unroll
    for (int t = 0; t < 4; t++)
#pragma unroll
      for (int j = 0; j < 16; j++)
        acc[j] = fmaf(xs[t], Wn[(q * 4 + t) * HD + c0 + j], acc[j]);
  }
#pragma unroll
  for (int j = 0; j < 16; j++) sh[slot * LP + c0 + j] = acc[j];
  if (valid) {
    float4* o = (float4*)(hA + (size_t)n * HD + c0);
    o[0] = make_float4(acc[0], acc[1], acc[2], acc[3]);
    o[1] = make_float4(acc[4], acc[5], acc[6], acc[7]);
    o[2] = make_float4(acc[8], acc[9], acc[10], acc[11]);
    o[3] = make_float4(acc[12], acc[13], acc[14], acc[15]);
  }
  __syncthreads();
  // stage 2 (K=64 from LDS)
  float a2[16];
#pragma unroll
  for (int j = 0; j < 16; j++) a2[j] = bl[c0 + j];
#pragma unroll 8
  for (int k = 0; k < 64; k++) {
    float hk = sh[slot * LP + k];
#pragma unroll
    for (int j = 0; j < 16; j++)
      a2[j] = fmaf(hk, Wl[k * HD + c0 + j], a2[j]);
  }
  float cn = 0.f, dn = 0.f;
#pragma unroll
  for (int j = 0; j < 16; j++) {
    cn = fmaf(a2[j], Wa[c0 + j], cn);
    dn = fmaf(a2[j], Wa[64 + c0 + j], dn);
  }
  if (valid) {
    float4* o = (float4*)(hB + (size_t)n * HD + c0);
    o[0] = make_float4(a2[0], a2[1], a2[2], a2[3]);
    o[1] = make_float4(a2[4], a2[5], a2[6], a2[7]);
    o[2] = make_float4(a2[8], a2[9], a2[10], a2[11]);
    o[3] = make_float4(a2[12], a2[13], a2[14], a2[15]);
  }
  sc[cc][slot] = cn;
  sd[cc][slot] = dn;
  __syncthreads();
  if (cc == 0 && valid) {
    cvec[n] = sc[0][slot] + sc[1][slot] + sc[2][slot] + sc[3][slot];
    dvec[n] = sd[0][slot] + sd[1][slot] + sd[2][slot] + sd[3][slot];
  }
}

// t = relu(BN1(hM@Wsl + hC@Wsr + bsl)) + hC -> hA, LDS ; hBp = dis*(t@Wg) -> hD
__global__ __launch_bounds__(256) void k_sagegcn(
    const float* __restrict__ hM, const float* __restrict__ hC,
    const float* __restrict__ Wl, const float* __restrict__ bl,
    const float* __restrict__ Wr, const float* __restrict__ Wg,
    const float* __restrict__ g, const float* __restrict__ bt,
    const float* __restrict__ dis,
    float* __restrict__ hA, float* __restrict__ hD) {
  __shared__ float sh[64 * LP];
  int slot = threadIdx.x & 63;
  int cc = __builtin_amdgcn_readfirstlane(threadIdx.x >> 6);
  int c0 = cc * 16;
  int n0 = blockIdx.x * 64 + slot;
  bool valid = n0 < NODES;
  int n = valid ? n0 : NODES - 1;
  const float4* mr = (const float4*)(hM + (size_t)n * HD);
  const float4* cr = (const float4*)(hC + (size_t)n * HD);
  float acc[16];
#pragma unroll
  for (int j = 0; j < 16; j++) acc[j] = bl[c0 + j];
#pragma unroll 4
  for (int q = 0; q < 16; q++) {
    float4 am = mr[q], ac = cr[q];
    float ms[4] = {am.x, am.y, am.z, am.w};
    float cs[4] = {ac.x, ac.y, ac.z, ac.w};
#pragma unroll
    for (int t = 0; t < 4; t++) {
      int k = q * 4 + t;
#pragma unroll
      for (int j = 0; j < 16; j++)
        acc[j] = fmaf(ms[t], Wl[k * HD + c0 + j], acc[j]);
#pragma unroll
      for (int j = 0; j < 16; j++)
        acc[j] = fmaf(cs[t], Wr[k * HD + c0 + j], acc[j]);
    }
  }
  float tv[16];
  {
    float4 r0 = cr[cc * 4 + 0], r1 = cr[cc * 4 + 1], r2 = cr[cc * 4 + 2], r3 = cr[cc * 4 + 3];
    float rv[16] = {r0.x, r0.y, r0.z, r0.w, r1.x, r1.y, r1.z, r1.w,
                    r2.x, r2.y, r2.z, r2.w, r3.x, r3.y, r3.z, r3.w};
#pragma unroll
    for (int j = 0; j < 16; j++)
      tv[j] = fmaxf(acc[j] * (g[c0 + j] * BN_INV) + bt[c0 + j], 0.f) + rv[j];
  }
#pragma unroll
  for (int j = 0; j < 16; j++) sh[slot * LP + c0 + j] = tv[j];
  if (valid) {
    float4* o = (float4*)(hA + (size_t)n * HD + c0);
    o[0] = make_float4(tv[0], tv[1], tv[2], tv[3]);
    o[1] = make_float4(tv[4], tv[5], tv[6], tv[7]);
    o[2] = make_float4(tv[8], tv[9], tv[10], tv[11]);
    o[3] = make_float4(tv[12], tv[13], tv[14], tv[15]);
  }
  __syncthreads();
  float di = dis[n];
  float a2[16];
#pragma unroll
  for (int j = 0; j < 16; j++) a2[j] = 0.f;
#pragma unroll 8
  for (int k = 0; k < 64; k++) {
    float tk = sh[slot * LP + k];
#pragma unroll
    for (int j = 0; j < 16; j++)
      a2[j] = fmaf(tk, Wg[k * HD + c0 + j], a2[j]);
  }
#pragma unroll
  for (int j = 0; j < 16; j++) a2[j] *= di;
  if (valid) {
    float4* o = (float4*)(hD + (size_t)n * HD + c0);
    o[0] = make_float4(a2[0], a2[1], a2[2], a2[3]);
    o[1] = make_float4(a2[4], a2[5], a2[6], a2[7]);
    o[2] = make_float4(a2[8], a2[9], a2[10], a2[11]);
    o[3] = make_float4(a2[12], a2[13], a2[14], a2[15]);
  }
}

// regressor head fused: out = relu(relu(hC@W1+b1)@W2+b2)@W3+b3
__global__ __launch_bounds__(256) void k_reg(
    const float* __restrict__ hC,
    const float* __restrict__ W1, const float* __restrict__ b1,
    const float* __restrict__ W2, const float* __restrict__ b2,
    const float* __restrict__ W3, const float* __restrict__ b3,
    float* __restrict__ out) {
  __shared__ float sh[64 * LP];
  __shared__ float sred[4][64];
  int slot = threadIdx.x & 63;
  int cc = __builtin_amdgcn_readfirstlane(threadIdx.x >> 6);
  int c0 = cc * 16;
  int n0 = blockIdx.x * 64 + slot;
  bool valid = n0 < NODES;
  int n = valid ? n0 : NODES - 1;
  const float4* cr = (const float4*)(hC + (size_t)n * HD);
  float acc[16];
#pragma unroll
  for (int j = 0; j < 16; j++) acc[j] = b1[c0 + j];
#pragma unroll 4
  for (int q = 0; q < 16; q++) {
    float4 ac = cr[q];
    float cs[4] = {ac.x, ac.y, ac.z, ac.w};
#pragma unroll
    for (int t = 0; t < 4; t++) {
      int k = q * 4 + t;
#pragma unroll
      for (int j = 0; j < 16; j++)
        acc[j] = fmaf(cs[t], W1[k * HD + c0 + j], acc[j]);
    }
  }
#pragma unroll
  for (int j = 0; j < 16; j++) sh[slot * LP + c0 + j] = fmaxf(acc[j], 0.f);
  __syncthreads();
  int d0 = cc * 8;
  float a2[8];
#pragma unroll
  for (int j = 0; j < 8; j++) a2[j] = b2[d0 + j];
#pragma unroll 8
  for (int k = 0; k < 64; k++) {
    float tk = sh[slot * LP + k];
#pragma unroll
    for (int j = 0; j < 8; j++)
      a2[j] = fmaf(tk, W2[k * 32 + d0 + j], a2[j]);
  }
  float part = 0.f;
#pragma unroll
  for (int j = 0; j < 8; j++) part = fmaf(fmaxf(a2[j], 0.f), W3[d0 + j], part);
  sred[cc][slot] = part;
  __syncthreads();
  if (cc == 0 && valid)
    out[n] = sred[0][slot] + sred[1][slot] + sred[2][slot] + sred[3][slot] + b3[0];
}

// ---------------- wave-per-node aggregations ----------------

#define AGG_BODY(TABLE, WEXPR0, WEXPR1, WEXPR2, WEXPR3)                          \
  float4 acc0 = make_float4(0.f, 0.f, 0.f, 0.f);                                 \
  float4 acc1 = make_float4(0.f, 0.f, 0.f, 0.f);                                 \
  float4 acc2 = make_float4(0.f, 0.f, 0.f, 0.f);                                 \
  float4 acc3 = make_float4(0.f, 0.f, 0.f, 0.f);                                 \
  int last = end - 1;                                                            \
  for (int m = start; m < end; m += 16) {                                        \
    int e0 = m + sub, e1 = e0 + 4, e2 = e0 + 8, e3 = e0 + 12;                    \
    float2 s0 = sa[min(e0, last)], s1 = sa[min(e1, last)];                       \
    float2 s2 = sa[min(e2, last)], s3 = sa[min(e3, last)];                       \
    float w0 = (e0 < end) ? (WEXPR0) : 0.f;                                      \
    float w1 = (e1 < end) ? (WEXPR1) : 0.f;                                      \
    float w2 = (e2 < end) ? (WEXPR2) : 0.f;                                      \
    float w3 = (e3 < end) ? (WEXPR3) : 0.f;                                      \
    float4 v0 = *((const float4*)(TABLE + (size_t)__float_as_int(s0.x) * HD) + col); \
    float4 v1 = *((const float4*)(TABLE + (size_t)__float_as_int(s1.x) * HD) + col); \
    float4 v2 = *((const float4*)(TABLE + (size_t)__float_as_int(s2.x) * HD) + col); \
    float4 v3 = *((const float4*)(TABLE + (size_t)__float_as_int(s3.x) * HD) + col); \
    acc0.x = fmaf(w0, v0.x, acc0.x); acc0.y = fmaf(w0, v0.y, acc0.y);            \
    acc0.z = fmaf(w0, v0.z, acc0.z); acc0.w = fmaf(w0, v0.w, acc0.w);            \
    acc1.x = fmaf(w1, v1.x, acc1.x); acc1.y = fmaf(w1, v1.y, acc1.y);            \
    acc1.z = fmaf(w1, v1.z, acc1.z); acc1.w = fmaf(w1, v1.w, acc1.w);            \
    acc2.x = fmaf(w2, v2.x, acc2.x); acc2.y = fmaf(w2, v2.y, acc2.y);            \
    acc2.z = fmaf(w2, v2.z, acc2.z); acc2.w = fmaf(w2, v2.w, acc2.w);            \
    acc3.x = fmaf(w3, v3.x, acc3.x); acc3.y = fmaf(w3, v3.y, acc3.y);            \
    acc3.z = fmaf(w3, v3.z, acc3.z); acc3.w = fmaf(w3, v3.w, acc3.w);            \
  }                                                                              \
  acc0.x = (acc0.x + acc1.x) + (acc2.x + acc3.x);                                \
  acc0.y = (acc0.y + acc1.y) + (acc2.y + acc3.y);                                \
  acc0.z = (acc0.z + acc1.z) + (acc2.z + acc3.z);                                \
  acc0.w = (acc0.w + acc1.w) + (acc2.w + acc3.w);                                \
  _Pragma("unroll")                                                              \
  for (int off = 16; off <= 32; off <<= 1) {                                     \
    acc0.x += __shfl_xor(acc0.x, off); acc0.y += __shfl_xor(acc0.y, off);        \
    acc0.z += __shfl_xor(acc0.z, off); acc0.w += __shfl_xor(acc0.w, off);        \
  }

__global__ __launch_bounds__(256) void k_agg_att(
    const float2* __restrict__ sa, const int* __restrict__ rowptr,
    const float* __restrict__ hA, const float* __restrict__ hB,
    const float* __restrict__ g, const float* __restrict__ bt,
    float* __restrict__ hC) {
  int lane = threadIdx.x & 63;
  int node = __builtin_amdgcn_readfirstlane(blockIdx.x * 4 + (threadIdx.x >> 6));
  if (node >= NODES) return;
  int start = rowptr[node], end = rowptr[node + 1];
  int sub = lane >> 4, col = lane & 15;
  float4 gg = ((const float4*)g)[col];
  float4 bb = ((const float4*)bt)[col];
  float4 ha = *((const float4*)(hA + (size_t)node * HD) + col);
  AGG_BODY(hB, s0.y, s1.y, s2.y, s3.y)
  if (lane < 16) {
    float4 v;
    v.x = fmaxf(acc0.x * (gg.x * BN_INV) + bb.x, 0.f) + ha.x;
    v.y = fmaxf(acc0.y * (gg.y * BN_INV) + bb.y, 0.f) + ha.y;
    v.z = fmaxf(acc0.z * (gg.z * BN_INV) + bb.z, 0.f) + ha.z;
    v.w = fmaxf(acc0.w * (gg.w * BN_INV) + bb.w, 0.f) + ha.w;
    *((float4*)(hC + (size_t)node * HD) + col) = v;
  }
}

__global__ __launch_bounds__(256) void k_agg_mean(
    const float2* __restrict__ sa, const int* __restrict__ rowptr,
    const float* __restrict__ hC, float* __restrict__ hM) {
  int lane = threadIdx.x & 63;
  int node = __builtin_amdgcn_readfirstlane(blockIdx.x * 4 + (threadIdx.x >> 6));
  if (node >= NODES) return;
  int start = rowptr[node], end = rowptr[node + 1];
  int sub = lane >> 4, col = lane & 15;
  float rdeg = 1.f / fmaxf((float)(end - start), 1.f);
  AGG_BODY(hC, 1.f, 1.f, 1.f, 1.f)
  if (lane < 16) {
    float4 v;
    v.x = acc0.x * rdeg; v.y = acc0.y * rdeg; v.z = acc0.z * rdeg; v.w = acc0.w * rdeg;
    *((float4*)(hM + (size_t)node * HD) + col) = v;
  }
}

__global__ __launch_bounds__(256) void k_agg_gcn(
    const float2* __restrict__ sa, const int* __restrict__ rowptr,
    const float* __restrict__ dis,
    const float* __restrict__ hA, const float* __restrict__ hBp,
    const float* __restrict__ bg,
    const float* __restrict__ g, const float* __restrict__ bt,
    float* __restrict__ hC) {
  int lane = threadIdx.x & 63;
  int node = __builtin_amdgcn_readfirstlane(blockIdx.x * 4 + (threadIdx.x >> 6));
  if (node >= NODES) return;
  int start = rowptr[node], end = rowptr[node + 1];
  int sub = lane >> 4, col = lane & 15;
  float di = dis[node];
  float4 sv = *((const float4*)(hBp + (size_t)node * HD) + col);  // self-loop
  float4 gg = ((const float4*)g)[col];
  float4 bb = ((const float4*)bt)[col];
  float4 ha = *((const float4*)(hA + (size_t)node * HD) + col);
  float4 bgv = ((const float4*)bg)[col];
  AGG_BODY(hBp, 1.f, 1.f, 1.f, 1.f)
  if (lane < 16) {
    float4 v;
    v.x = fmaxf((di * (acc0.x + sv.x) + bgv.x) * (gg.x * BN_INV) + bb.x, 0.f) + ha.x;
    v.y = fmaxf((di * (acc0.y + sv.y) + bgv.y) * (gg.y * BN_INV) + bb.y, 0.f) + ha.y;
    v.z = fmaxf((di * (acc0.z + sv.z) + bgv.z) * (gg.z * BN_INV) + bb.z, 0.f) + ha.z;
    v.w = fmaxf((di * (acc0.w + sv.w) + bgv.w) * (gg.w * BN_INV) + bb.w, 0.f) + ha.w;
    *((float4*)(hC + (size_t)node * HD) + col) = v;
  }
}

// ---------------- host launch ----------------

extern "C" void kernel_launch(void* const* d_in, const int* in_sizes, int n_in,
                              void* d_out, int out_size, void* d_ws, size_t ws_size,
                              hipStream_t stream) {
  const float* x      = (const float*)d_in[0];
  const float* ea     = (const float*)d_in[1];
  const int*   ei     = (const int*)d_in[2];
  const float* W_node = (const float*)d_in[3];
  const float* b_node = (const float*)d_in[4];
  // d_in[5], d_in[6]: W_edge/b_edge — unused by the reference output
  const float* W_lin0 = (const float*)d_in[7];
  const float* b_lin0 = (const float*)d_in[8];
  const float* W_att0 = (const float*)d_in[9];
  const float* b_att0 = (const float*)d_in[10];
  const float* W_sl   = (const float*)d_in[11];
  const float* b_sl   = (const float*)d_in[12];
  const float* W_sr   = (const float*)d_in[13];
  const float* W_gcn  = (const float*)d_in[14];
  const float* b_gcn  = (const float*)d_in[15];
  const float* bn_g   = (const float*)d_in[16];  // [3,64]
  const float* bn_b   = (const float*)d_in[17];
  const float* W_r1   = (const float*)d_in[18];
  const float* b_r1   = (const float*)d_in[19];
  const float* W_r2   = (const float*)d_in[20];
  const float* b_r2   = (const float*)d_in[21];
  const float* W_r3   = (const float*)d_in[22];
  const float* b_r3   = (const float*)d_in[23];
  float* out = (float*)d_out;

  char* ws = (char*)d_ws;
  size_t o = 0;
  auto alloc = [&](size_t bytes) -> void* {
    void* p = ws + o;
    o += (bytes + 255) & ~(size_t)255;
    return p;
  };
  int*    deg    = (int*)alloc(NODES * 4);
  int*    rowptr = (int*)alloc((NODES + 1) * 4);
  int*    cur    = (int*)alloc(NODES * 4);
  int*    part   = (int*)alloc(256 * 4);   // also reused as bucket cursors
  float2* sa     = (float2*)alloc((size_t)EDGES * 8);
  float*  hA     = (float*)alloc((size_t)NODES * HD * 4);
  float*  hB     = (float*)alloc((size_t)NODES * HD * 4);
  float*  hC     = (float*)alloc((size_t)NODES * HD * 4);
  float*  hD     = (float*)alloc((size_t)NODES * HD * 4);
  float*  cvec   = (float*)alloc(NODES * 4);
  float*  dvec   = (float*)alloc(NODES * 4);
  float*  dis    = (float*)alloc(NODES * 4);
  // tmp (20 MB) aliases hD (25.6 MB): dead before k_sagegcn writes hD
  float4* tmp    = (float4*)hD;
  int*    gcur   = part;
  (void)ws_size; (void)in_sizes; (void)n_in; (void)out_size;

  const int EB  = (EDGES + 255) / 256;
  const int BB  = (EDGES + 2047) / 2048;  // k_bucket blocks
  const int NT  = (NODES + 63) / 64;      // 64 nodes/block, 256 threads
  const int NBW = (NODES + 3) / 4;        // wave-per-node (4 waves/block)

  hipMemsetAsync(deg, 0, NODES * 4, stream);
  k_hist<<<EB, 256, 0, stream>>>(ei, deg);
  k_scan1<<<NCHUNK, 256, 0, stream>>>(deg, part);
  k_scan2<<<1, 64, 0, stream>>>(part);
  k_scan3<<<NCHUNK, 256, 0, stream>>>(deg, part, rowptr, cur, dis);
  k_binit<<<1, 128, 0, stream>>>(rowptr, gcur);

  k_lin0<<<NT, 256, 0, stream>>>(x, W_node, b_node, W_lin0, b_lin0, W_att0,
                                 hA, hB, cvec, dvec);
  k_bucket<<<BB, 256, 0, stream>>>(ei, ea, cvec, dvec, W_att0, b_att0, gcur, tmp);
  k_fine<<<NBKT, 512, 0, stream>>>(tmp, rowptr, cur, sa);
  k_agg_att<<<NBW, 256, 0, stream>>>(sa, rowptr, hA, hB,
                                     bn_g + 0 * HD, bn_b + 0 * HD, hC);
  // hB (h0) dead -> reuse as mean buffer
  k_agg_mean<<<NBW, 256, 0, stream>>>(sa, rowptr, hC, hB);
  // t -> hA (h dead), hBp -> hD (tmp dead)
  k_sagegcn<<<NT, 256, 0, stream>>>(hB, hC, W_sl, b_sl, W_sr, W_gcn,
                                    bn_g + 1 * HD, bn_b + 1 * HD, dis, hA, hD);
  k_agg_gcn<<<NBW, 256, 0, stream>>>(sa, rowptr, dis, hA, hD, b_gcn,
                                     bn_g + 2 * HD, bn_b + 2 * HD, hC);
  k_reg<<<NT, 256, 0, stream>>>(hC, W_r1, b_r1, W_r2, b_r2, W_r3, b_r3, out);
}

// Round 9
// 379.551 us; speedup vs baseline: 1.0051x; 1.0051x over previous
//
#include <hip/hip_runtime.h>
#include <math.h>

#define NODES 100000
#define EDGES 1250000
#define HD 64
#define NFD 16
#define CHUNK 1024
#define NCHUNK ((NODES + CHUNK - 1) / CHUNK)
#define BN_INV 0.9999950000374996f  // 1/sqrt(1+1e-5)
#define LP 65  // LDS row pitch: 65 % 32 == 1 -> 2-way bank aliasing (free)

// ---------------- graph build ----------------

__global__ void k_hist(const int* __restrict__ ei, int* __restrict__ deg) {
  int e = blockIdx.x * blockDim.x + threadIdx.x;
  if (e < EDGES) atomicAdd(&deg[ei[EDGES + e]], 1);
}

__global__ void k_scan1(const int* __restrict__ deg, int* __restrict__ part) {
  __shared__ int lds[256];
  int t = threadIdx.x, b = blockIdx.x;
  int base = b * CHUNK + t * 4;
  int s = 0;
#pragma unroll
  for (int m = 0; m < 4; m++) { int i = base + m; if (i < NODES) s += deg[i]; }
  lds[t] = s; __syncthreads();
  for (int off = 128; off > 0; off >>= 1) {
    if (t < off) lds[t] += lds[t + off];
    __syncthreads();
  }
  if (t == 0) part[b] = lds[0];
}

__global__ void k_scan2(int* __restrict__ part) {
  if (threadIdx.x == 0 && blockIdx.x == 0) {
    int run = 0;
    for (int c = 0; c < NCHUNK; c++) { int v = part[c]; part[c] = run; run += v; }
  }
}

__global__ void k_scan3(const int* __restrict__ deg, const int* __restrict__ part,
                        int* __restrict__ rowptr, int* __restrict__ cur,
                        float* __restrict__ dis) {
  __shared__ int lds[256];
  int t = threadIdx.x, b = blockIdx.x;
  int base = b * CHUNK + t * 4;
  int dl[4]; int s = 0;
#pragma unroll
  for (int m = 0; m < 4; m++) { int i = base + m; dl[m] = (i < NODES) ? deg[i] : 0; s += dl[m]; }
  lds[t] = s; __syncthreads();
  for (int off = 1; off < 256; off <<= 1) {
    int add = (t >= off) ? lds[t - off] : 0;
    __syncthreads();
    lds[t] += add;
    __syncthreads();
  }
  int run = part[b] + lds[t] - s;  // exclusive prefix for this thread
#pragma unroll
  for (int m = 0; m < 4; m++) {
    int i = base + m;
    if (i < NODES) {
      rowptr[i] = run; cur[i] = run;
      dis[i] = 1.0f / sqrtf((float)(dl[m] + 1));  // GCN: indeg + self-loop
    }
    run += dl[m];
  }
  if (b == 0 && t == 0) rowptr[NODES] = EDGES;
}

// attention coeff in ORIGINAL edge order, then single 8B scattered write
__global__ void k_fillatt(const int* __restrict__ ei, const float* __restrict__ ea,
                          const float* __restrict__ cvec, const float* __restrict__ dvec,
                          const float* __restrict__ Wa, const float* __restrict__ ba,
                          int* __restrict__ cur, float2* __restrict__ sa) {
  int e = blockIdx.x * blockDim.x + threadIdx.x;
  if (e >= EDGES) return;
  int s = ei[e], d = ei[EDGES + e];
  float alin = cvec[d] + dvec[s] + ea[3 * e] * Wa[128] + ea[3 * e + 1] * Wa[129] +
               ea[3 * e + 2] * Wa[130] + ba[0];
  float lr = alin >= 0.f ? alin : 0.01f * alin;
  float a = 1.f / (1.f + expf(-lr));
  int p = atomicAdd(&cur[d], 1);
  sa[p] = make_float2(__int_as_float(s), a);
}

// ---------------- gather macro (16 edges/iter, 4 gathers in flight) ----------------

#define AGG_BODY(TABLE, WEXPR0, WEXPR1, WEXPR2, WEXPR3)                          \
  float4 acc0 = make_float4(0.f, 0.f, 0.f, 0.f);                                 \
  float4 acc1 = make_float4(0.f, 0.f, 0.f, 0.f);                                 \
  float4 acc2 = make_float4(0.f, 0.f, 0.f, 0.f);                                 \
  float4 acc3 = make_float4(0.f, 0.f, 0.f, 0.f);                                 \
  int last = end - 1;                                                            \
  for (int m = start; m < end; m += 16) {                                        \
    int e0 = m + sub, e1 = e0 + 4, e2 = e0 + 8, e3 = e0 + 12;                    \
    float2 s0 = sa[min(e0, last)], s1 = sa[min(e1, last)];                       \
    float2 s2 = sa[min(e2, last)], s3 = sa[min(e3, last)];                       \
    float w0 = (e0 < end) ? (WEXPR0) : 0.f;                                      \
    float w1 = (e1 < end) ? (WEXPR1) : 0.f;                                      \
    float w2 = (e2 < end) ? (WEXPR2) : 0.f;                                      \
    float w3 = (e3 < end) ? (WEXPR3) : 0.f;                                      \
    float4 v0 = *((const float4*)(TABLE + (size_t)__float_as_int(s0.x) * HD) + col); \
    float4 v1 = *((const float4*)(TABLE + (size_t)__float_as_int(s1.x) * HD) + col); \
    float4 v2 = *((const float4*)(TABLE + (size_t)__float_as_int(s2.x) * HD) + col); \
    float4 v3 = *((const float4*)(TABLE + (size_t)__float_as_int(s3.x) * HD) + col); \
    acc0.x = fmaf(w0, v0.x, acc0.x); acc0.y = fmaf(w0, v0.y, acc0.y);            \
    acc0.z = fmaf(w0, v0.z, acc0.z); acc0.w = fmaf(w0, v0.w, acc0.w);            \
    acc1.x = fmaf(w1, v1.x, acc1.x); acc1.y = fmaf(w1, v1.y, acc1.y);            \
    acc1.z = fmaf(w1, v1.z, acc1.z); acc1.w = fmaf(w1, v1.w, acc1.w);            \
    acc2.x = fmaf(w2, v2.x, acc2.x); acc2.y = fmaf(w2, v2.y, acc2.y);            \
    acc2.z = fmaf(w2, v2.z, acc2.z); acc2.w = fmaf(w2, v2.w, acc2.w);            \
    acc3.x = fmaf(w3, v3.x, acc3.x); acc3.y = fmaf(w3, v3.y, acc3.y);            \
    acc3.z = fmaf(w3, v3.z, acc3.z); acc3.w = fmaf(w3, v3.w, acc3.w);            \
  }                                                                              \
  acc0.x = (acc0.x + acc1.x) + (acc2.x + acc3.x);                                \
  acc0.y = (acc0.y + acc1.y) + (acc2.y + acc3.y);                                \
  acc0.z = (acc0.z + acc1.z) + (acc2.z + acc3.z);                                \
  acc0.w = (acc0.w + acc1.w) + (acc2.w + acc3.w);                                \
  _Pragma("unroll")                                                              \
  for (int off = 16; off <= 32; off <<= 1) {                                     \
    acc0.x += __shfl_xor(acc0.x, off); acc0.y += __shfl_xor(acc0.y, off);        \
    acc0.z += __shfl_xor(acc0.z, off); acc0.w += __shfl_xor(acc0.w, off);        \
  }

// ---------------- kernels ----------------

// lin0: h = x@Wn + bn -> hA, LDS ; h0 = h@Wl + bl -> hB ; cvec/dvec dots
__global__ __launch_bounds__(256) void k_lin0(
    const float* __restrict__ x,
    const float* __restrict__ Wn, const float* __restrict__ bn,
    const float* __restrict__ Wl, const float* __restrict__ bl,
    const float* __restrict__ Wa,
    float* __restrict__ hA, float* __restrict__ hB,
    float* __restrict__ cvec, float* __restrict__ dvec) {
  __shared__ float sh[64 * LP];
  __shared__ float sc[4][64], sd[4][64];
  int slot = threadIdx.x & 63;
  int cc = __builtin_amdgcn_readfirstlane(threadIdx.x >> 6);
  int c0 = cc * 16;
  int n0 = blockIdx.x * 64 + slot;
  bool valid = n0 < NODES;
  int n = valid ? n0 : NODES - 1;
  const float4* xr = (const float4*)(x + (size_t)n * NFD);
  float acc[16];
#pragma unroll
  for (int j = 0; j < 16; j++) acc[j] = bn[c0 + j];
#pragma unroll
  for (int q = 0; q < 4; q++) {
    float4 xa = xr[q];
    float xs[4] = {xa.x, xa.y, xa.z, xa.w};
#pragma unroll
    for (int t = 0; t < 4; t++)
#pragma unroll
      for (int j = 0; j < 16; j++)
        acc[j] = fmaf(xs[t], Wn[(q * 4 + t) * HD + c0 + j], acc[j]);
  }
#pragma unroll
  for (int j = 0; j < 16; j++) sh[slot * LP + c0 + j] = acc[j];
  if (valid) {
    float4* o = (float4*)(hA + (size_t)n * HD + c0);
    o[0] = make_float4(acc[0], acc[1], acc[2], acc[3]);
    o[1] = make_float4(acc[4], acc[5], acc[6], acc[7]);
    o[2] = make_float4(acc[8], acc[9], acc[10], acc[11]);
    o[3] = make_float4(acc[12], acc[13], acc[14], acc[15]);
  }
  __syncthreads();
  float a2[16];
#pragma unroll
  for (int j = 0; j < 16; j++) a2[j] = bl[c0 + j];
#pragma unroll 8
  for (int k = 0; k < 64; k++) {
    float hk = sh[slot * LP + k];
#pragma unroll
    for (int j = 0; j < 16; j++)
      a2[j] = fmaf(hk, Wl[k * HD + c0 + j], a2[j]);
  }
  float cn = 0.f, dn = 0.f;
#pragma unroll
  for (int j = 0; j < 16; j++) {
    cn = fmaf(a2[j], Wa[c0 + j], cn);
    dn = fmaf(a2[j], Wa[64 + c0 + j], dn);
  }
  if (valid) {
    float4* o = (float4*)(hB + (size_t)n * HD + c0);
    o[0] = make_float4(a2[0], a2[1], a2[2], a2[3]);
    o[1] = make_float4(a2[4], a2[5], a2[6], a2[7]);
    o[2] = make_float4(a2[8], a2[9], a2[10], a2[11]);
    o[3] = make_float4(a2[12], a2[13], a2[14], a2[15]);
  }
  sc[cc][slot] = cn;
  sd[cc][slot] = dn;
  __syncthreads();
  if (cc == 0 && valid) {
    cvec[n] = sc[0][slot] + sc[1][slot] + sc[2][slot] + sc[3][slot];
    dvec[n] = sd[0][slot] + sd[1][slot] + sd[2][slot] + sd[3][slot];
  }
}

// layer0 aggregation (standalone: output hC feeds a cross-block gather next)
__global__ __launch_bounds__(256) void k_agg_att(
    const float2* __restrict__ sa, const int* __restrict__ rowptr,
    const float* __restrict__ hA, const float* __restrict__ hB,
    const float* __restrict__ g, const float* __restrict__ bt,
    float* __restrict__ hC) {
  int lane = threadIdx.x & 63;
  int node = __builtin_amdgcn_readfirstlane(blockIdx.x * 4 + (threadIdx.x >> 6));
  if (node >= NODES) return;
  int start = rowptr[node], end = rowptr[node + 1];
  int sub = lane >> 4, col = lane & 15;
  float4 gg = ((const float4*)g)[col];
  float4 bb = ((const float4*)bt)[col];
  float4 ha = *((const float4*)(hA + (size_t)node * HD) + col);
  AGG_BODY(hB, s0.y, s1.y, s2.y, s3.y)
  if (lane < 16) {
    float4 v;
    v.x = fmaxf(acc0.x * (gg.x * BN_INV) + bb.x, 0.f) + ha.x;
    v.y = fmaxf(acc0.y * (gg.y * BN_INV) + bb.y, 0.f) + ha.y;
    v.z = fmaxf(acc0.z * (gg.z * BN_INV) + bb.z, 0.f) + ha.z;
    v.w = fmaxf(acc0.w * (gg.w * BN_INV) + bb.w, 0.f) + ha.w;
    *((float4*)(hC + (size_t)node * HD) + col) = v;
  }
}

// FUSED mean-gather + SAGE + GCN pre-GEMM.
// phase 1: each wave mean-gathers 16 of the block's 64 nodes -> LDS rows.
// phase 2: cc-split GEMMs (Wl from LDS mean, Wr from global hC row),
//          BN+relu+residual -> t -> hA & LDS; then dis*(t@Wg) -> hD.
__global__ __launch_bounds__(256) void k_msage(
    const float2* __restrict__ sa, const int* __restrict__ rowptr,
    const float* __restrict__ hC,
    const float* __restrict__ Wl, const float* __restrict__ bl,
    const float* __restrict__ Wr, const float* __restrict__ Wg,
    const float* __restrict__ g, const float* __restrict__ bt,
    const float* __restrict__ dis,
    float* __restrict__ hA, float* __restrict__ hD) {
  __shared__ float sh[64 * LP];
  int lane = threadIdx.x & 63;
  int wu = __builtin_amdgcn_readfirstlane(threadIdx.x >> 6);
  int sub = lane >> 4, col = lane & 15;
  int nbase = blockIdx.x * 64;
  // phase 1: mean-gather
  for (int i = 0; i < 16; i++) {
    int slot = wu * 16 + i;
    int nn = min(nbase + slot, NODES - 1);
    int start = rowptr[nn], end = rowptr[nn + 1];
    float rdeg = 1.f / fmaxf((float)(end - start), 1.f);
    AGG_BODY(hC, 1.f, 1.f, 1.f, 1.f)
    if (lane < 16) {
      sh[slot * LP + col * 4 + 0] = acc0.x * rdeg;
      sh[slot * LP + col * 4 + 1] = acc0.y * rdeg;
      sh[slot * LP + col * 4 + 2] = acc0.z * rdeg;
      sh[slot * LP + col * 4 + 3] = acc0.w * rdeg;
    }
  }
  __syncthreads();
  // phase 2: GEMMs
  int c0 = wu * 16;
  int n0 = nbase + lane;
  bool valid = n0 < NODES;
  int n = valid ? n0 : NODES - 1;
  const float4* cr = (const float4*)(hC + (size_t)n * HD);
  float acc[16];
#pragma unroll
  for (int j = 0; j < 16; j++) acc[j] = bl[c0 + j];
#pragma unroll 8
  for (int k = 0; k < 64; k++) {
    float mk = sh[lane * LP + k];
#pragma unroll
    for (int j = 0; j < 16; j++)
      acc[j] = fmaf(mk, Wl[k * HD + c0 + j], acc[j]);
  }
#pragma unroll 4
  for (int q = 0; q < 16; q++) {
    float4 ac = cr[q];
    float cs[4] = {ac.x, ac.y, ac.z, ac.w};
#pragma unroll
    for (int t = 0; t < 4; t++)
#pragma unroll
      for (int j = 0; j < 16; j++)
        acc[j] = fmaf(cs[t], Wr[(q * 4 + t) * HD + c0 + j], acc[j]);
  }
  float tv[16];
  {
    float4 r0 = cr[wu * 4 + 0], r1 = cr[wu * 4 + 1], r2 = cr[wu * 4 + 2], r3 = cr[wu * 4 + 3];
    float rv[16] = {r0.x, r0.y, r0.z, r0.w, r1.x, r1.y, r1.z, r1.w,
                    r2.x, r2.y, r2.z, r2.w, r3.x, r3.y, r3.z, r3.w};
#pragma unroll
    for (int j = 0; j < 16; j++)
      tv[j] = fmaxf(acc[j] * (g[c0 + j] * BN_INV) + bt[c0 + j], 0.f) + rv[j];
  }
  __syncthreads();  // mean rows fully consumed -> safe to overwrite
#pragma unroll
  for (int j = 0; j < 16; j++) sh[lane * LP + c0 + j] = tv[j];
  if (valid) {
    float4* o = (float4*)(hA + (size_t)n * HD + c0);
    o[0] = make_float4(tv[0], tv[1], tv[2], tv[3]);
    o[1] = make_float4(tv[4], tv[5], tv[6], tv[7]);
    o[2] = make_float4(tv[8], tv[9], tv[10], tv[11]);
    o[3] = make_float4(tv[12], tv[13], tv[14], tv[15]);
  }
  __syncthreads();
  float di = dis[n];
  float a2[16];
#pragma unroll
  for (int j = 0; j < 16; j++) a2[j] = 0.f;
#pragma unroll 8
  for (int k = 0; k < 64; k++) {
    float tk = sh[lane * LP + k];
#pragma unroll
    for (int j = 0; j < 16; j++)
      a2[j] = fmaf(tk, Wg[k * HD + c0 + j], a2[j]);
  }
#pragma unroll
  for (int j = 0; j < 16; j++) a2[j] *= di;
  if (valid) {
    float4* o = (float4*)(hD + (size_t)n * HD + c0);
    o[0] = make_float4(a2[0], a2[1], a2[2], a2[3]);
    o[1] = make_float4(a2[4], a2[5], a2[6], a2[7]);
    o[2] = make_float4(a2[8], a2[9], a2[10], a2[11]);
    o[3] = make_float4(a2[12], a2[13], a2[14], a2[15]);
  }
}

// FUSED GCN aggregation + regressor head -> out (final hC never materialized)
__global__ __launch_bounds__(256) void k_gcnreg(
    const float2* __restrict__ sa, const int* __restrict__ rowptr,
    const float* __restrict__ dis,
    const float* __restrict__ hA,   // t (residual ident)
    const float* __restrict__ hD,   // hBp = dis*(t@Wg)
    const float* __restrict__ bg,
    const float* __restrict__ g, const float* __restrict__ bt,
    const float* __restrict__ W1, const float* __restrict__ b1,
    const float* __restrict__ W2, const float* __restrict__ b2,
    const float* __restrict__ W3, const float* __restrict__ b3,
    float* __restrict__ out) {
  __shared__ float sh[64 * LP];
  __shared__ float sred[4][64];
  int lane = threadIdx.x & 63;
  int wu = __builtin_amdgcn_readfirstlane(threadIdx.x >> 6);
  int sub = lane >> 4, col = lane & 15;
  int nbase = blockIdx.x * 64;
  float4 gg = ((const float4*)g)[col];
  float4 bb = ((const float4*)bt)[col];
  float4 bgv = ((const float4*)bg)[col];
  // phase 1: gcn-gather + epilogue -> layer2 output rows in LDS
  for (int i = 0; i < 16; i++) {
    int slot = wu * 16 + i;
    int nn = min(nbase + slot, NODES - 1);
    int start = rowptr[nn], end = rowptr[nn + 1];
    float di = dis[nn];
    float4 sv = *((const float4*)(hD + (size_t)nn * HD) + col);  // self-loop
    float4 ha = *((const float4*)(hA + (size_t)nn * HD) + col);
    AGG_BODY(hD, 1.f, 1.f, 1.f, 1.f)
    if (lane < 16) {
      sh[slot * LP + col * 4 + 0] =
          fmaxf((di * (acc0.x + sv.x) + bgv.x) * (gg.x * BN_INV) + bb.x, 0.f) + ha.x;
      sh[slot * LP + col * 4 + 1] =
          fmaxf((di * (acc0.y + sv.y) + bgv.y) * (gg.y * BN_INV) + bb.y, 0.f) + ha.y;
      sh[slot * LP + col * 4 + 2] =
          fmaxf((di * (acc0.z + sv.z) + bgv.z) * (gg.z * BN_INV) + bb.z, 0.f) + ha.z;
      sh[slot * LP + col * 4 + 3] =
          fmaxf((di * (acc0.w + sv.w) + bgv.w) * (gg.w * BN_INV) + bb.w, 0.f) + ha.w;
    }
  }
  __syncthreads();
  // phase 2: regressor GEMM chain from LDS
  int c0 = wu * 16;
  int n0 = nbase + lane;
  bool valid = n0 < NODES;
  int n = valid ? n0 : NODES - 1;
  float acc[16];
#pragma unroll
  for (int j = 0; j < 16; j++) acc[j] = b1[c0 + j];
#pragma unroll 8
  for (int k = 0; k < 64; k++) {
    float rk = sh[lane * LP + k];
#pragma unroll
    for (int j = 0; j < 16; j++)
      acc[j] = fmaf(rk, W1[k * HD + c0 + j], acc[j]);
  }
  float t1v[16];
#pragma unroll
  for (int j = 0; j < 16; j++) t1v[j] = fmaxf(acc[j], 0.f);
  __syncthreads();  // layer2 rows consumed -> overwrite with t1
#pragma unroll
  for (int j = 0; j < 16; j++) sh[lane * LP + c0 + j] = t1v[j];
  __syncthreads();
  int d0 = wu * 8;
  float a2[8];
#pragma unroll
  for (int j = 0; j < 8; j++) a2[j] = b2[d0 + j];
#pragma unroll 8
  for (int k = 0; k < 64; k++) {
    float tk = sh[lane * LP + k];
#pragma unroll
    for (int j = 0; j < 8; j++)
      a2[j] = fmaf(tk, W2[k * 32 + d0 + j], a2[j]);
  }
  float part = 0.f;
#pragma unroll
  for (int j = 0; j < 8; j++) part = fmaf(fmaxf(a2[j], 0.f), W3[d0 + j], part);
  sred[wu][lane] = part;
  __syncthreads();
  if (wu == 0 && valid)
    out[n] = sred[0][lane] + sred[1][lane] + sred[2][lane] + sred[3][lane] + b3[0];
}

// ---------------- host launch ----------------

extern "C" void kernel_launch(void* const* d_in, const int* in_sizes, int n_in,
                              void* d_out, int out_size, void* d_ws, size_t ws_size,
                              hipStream_t stream) {
  const float* x      = (const float*)d_in[0];
  const float* ea     = (const float*)d_in[1];
  const int*   ei     = (const int*)d_in[2];
  const float* W_node = (const float*)d_in[3];
  const float* b_node = (const float*)d_in[4];
  // d_in[5], d_in[6]: W_edge/b_edge — unused by the reference output
  const float* W_lin0 = (const float*)d_in[7];
  const float* b_lin0 = (const float*)d_in[8];
  const float* W_att0 = (const float*)d_in[9];
  const float* b_att0 = (const float*)d_in[10];
  const float* W_sl   = (const float*)d_in[11];
  const float* b_sl   = (const float*)d_in[12];
  const float* W_sr   = (const float*)d_in[13];
  const float* W_gcn  = (const float*)d_in[14];
  const float* b_gcn  = (const float*)d_in[15];
  const float* bn_g   = (const float*)d_in[16];  // [3,64]
  const float* bn_b   = (const float*)d_in[17];
  const float* W_r1   = (const float*)d_in[18];
  const float* b_r1   = (const float*)d_in[19];
  const float* W_r2   = (const float*)d_in[20];
  const float* b_r2   = (const float*)d_in[21];
  const float* W_r3   = (const float*)d_in[22];
  const float* b_r3   = (const float*)d_in[23];
  float* out = (float*)d_out;

  char* ws = (char*)d_ws;
  size_t o = 0;
  auto alloc = [&](size_t bytes) -> void* {
    void* p = ws + o;
    o += (bytes + 255) & ~(size_t)255;
    return p;
  };
  int*    deg    = (int*)alloc(NODES * 4);
  int*    rowptr = (int*)alloc((NODES + 1) * 4);
  int*    cur    = (int*)alloc(NODES * 4);
  int*    part   = (int*)alloc(256 * 4);
  float2* sa     = (float2*)alloc((size_t)EDGES * 8);
  float*  hA     = (float*)alloc((size_t)NODES * HD * 4);
  float*  hB     = (float*)alloc((size_t)NODES * HD * 4);
  float*  hC     = (float*)alloc((size_t)NODES * HD * 4);
  float*  hD     = (float*)alloc((size_t)NODES * HD * 4);
  float*  cvec   = (float*)alloc(NODES * 4);
  float*  dvec   = (float*)alloc(NODES * 4);
  float*  dis    = (float*)alloc(NODES * 4);
  (void)ws_size; (void)in_sizes; (void)n_in; (void)out_size;

  const int EB  = (EDGES + 255) / 256;
  const int NT  = (NODES + 63) / 64;     // 64 nodes/block, 256 threads
  const int NBW = (NODES + 3) / 4;       // wave-per-node (4 waves/block)

  hipMemsetAsync(deg, 0, NODES * 4, stream);
  k_hist<<<EB, 256, 0, stream>>>(ei, deg);
  k_scan1<<<NCHUNK, 256, 0, stream>>>(deg, part);
  k_scan2<<<1, 64, 0, stream>>>(part);
  k_scan3<<<NCHUNK, 256, 0, stream>>>(deg, part, rowptr, cur, dis);

  k_lin0<<<NT, 256, 0, stream>>>(x, W_node, b_node, W_lin0, b_lin0, W_att0,
                                 hA, hB, cvec, dvec);
  k_fillatt<<<EB, 256, 0, stream>>>(ei, ea, cvec, dvec, W_att0, b_att0, cur, sa);
  k_agg_att<<<NBW, 256, 0, stream>>>(sa, rowptr, hA, hB,
                                     bn_g + 0 * HD, bn_b + 0 * HD, hC);
  // fused mean-gather + SAGE + GCN pre-GEMM: t -> hA (h dead), hBp -> hD
  k_msage<<<NT, 256, 0, stream>>>(sa, rowptr, hC, W_sl, b_sl, W_sr, W_gcn,
                                  bn_g + 1 * HD, bn_b + 1 * HD, dis, hA, hD);
  // fused GCN aggregation + regressor -> out
  k_gcnreg<<<NT, 256, 0, stream>>>(sa, rowptr, dis, hA, hD, b_gcn,
                                   bn_g + 2 * HD, bn_b + 2 * HD,
                                   W_r1, b_r1, W_r2, b_r2, W_r3, b_r3, out);
}

// Round 10
// 341.324 us; speedup vs baseline: 1.1177x; 1.1120x over previous
//
#include <hip/hip_runtime.h>
#include <hip/hip_fp16.h>
#include <math.h>

#define NODES 100000
#define EDGES 1250000
#define HD 64
#define NFD 16
#define CHUNK 1024
#define NCHUNK ((NODES + CHUNK - 1) / CHUNK)
#define BN_INV 0.9999950000374996f  // 1/sqrt(1+1e-5)
#define LP 65  // LDS row pitch: 65 % 32 == 1 -> 2-way bank aliasing (free)

// ---------------- graph build ----------------

__global__ void k_hist(const int* __restrict__ ei, int* __restrict__ deg) {
  int e = blockIdx.x * blockDim.x + threadIdx.x;
  if (e < EDGES) atomicAdd(&deg[ei[EDGES + e]], 1);
}

__global__ void k_scan1(const int* __restrict__ deg, int* __restrict__ part) {
  __shared__ int lds[256];
  int t = threadIdx.x, b = blockIdx.x;
  int base = b * CHUNK + t * 4;
  int s = 0;
#pragma unroll
  for (int m = 0; m < 4; m++) { int i = base + m; if (i < NODES) s += deg[i]; }
  lds[t] = s; __syncthreads();
  for (int off = 128; off > 0; off >>= 1) {
    if (t < off) lds[t] += lds[t + off];
    __syncthreads();
  }
  if (t == 0) part[b] = lds[0];
}

__global__ void k_scan2(int* __restrict__ part) {
  if (threadIdx.x == 0 && blockIdx.x == 0) {
    int run = 0;
    for (int c = 0; c < NCHUNK; c++) { int v = part[c]; part[c] = run; run += v; }
  }
}

__global__ void k_scan3(const int* __restrict__ deg, const int* __restrict__ part,
                        int* __restrict__ rowptr, int* __restrict__ cur,
                        float* __restrict__ dis) {
  __shared__ int lds[256];
  int t = threadIdx.x, b = blockIdx.x;
  int base = b * CHUNK + t * 4;
  int dl[4]; int s = 0;
#pragma unroll
  for (int m = 0; m < 4; m++) { int i = base + m; dl[m] = (i < NODES) ? deg[i] : 0; s += dl[m]; }
  lds[t] = s; __syncthreads();
  for (int off = 1; off < 256; off <<= 1) {
    int add = (t >= off) ? lds[t - off] : 0;
    __syncthreads();
    lds[t] += add;
    __syncthreads();
  }
  int run = part[b] + lds[t] - s;  // exclusive prefix for this thread
#pragma unroll
  for (int m = 0; m < 4; m++) {
    int i = base + m;
    if (i < NODES) {
      rowptr[i] = run; cur[i] = run;
      dis[i] = 1.0f / sqrtf((float)(dl[m] + 1));  // GCN: indeg + self-loop
    }
    run += dl[m];
  }
  if (b == 0 && t == 0) rowptr[NODES] = EDGES;
}

// attention coeff in ORIGINAL edge order, then single 8B scattered write
__global__ void k_fillatt(const int* __restrict__ ei, const float* __restrict__ ea,
                          const float* __restrict__ cvec, const float* __restrict__ dvec,
                          const float* __restrict__ Wa, const float* __restrict__ ba,
                          int* __restrict__ cur, float2* __restrict__ sa) {
  int e = blockIdx.x * blockDim.x + threadIdx.x;
  if (e >= EDGES) return;
  int s = ei[e], d = ei[EDGES + e];
  float alin = cvec[d] + dvec[s] + ea[3 * e] * Wa[128] + ea[3 * e + 1] * Wa[129] +
               ea[3 * e + 2] * Wa[130] + ba[0];
  float lr = alin >= 0.f ? alin : 0.01f * alin;
  float a = 1.f / (1.f + expf(-lr));
  int p = atomicAdd(&cur[d], 1);
  sa[p] = make_float2(__int_as_float(s), a);
}

// ---------------- fp16 row helpers ----------------

__device__ __forceinline__ void store16h(__half* dst, const float* v) {
  uint u[8];
#pragma unroll
  for (int j = 0; j < 8; j++) {
    __half2 h = __float22half2_rn(make_float2(v[2 * j], v[2 * j + 1]));
    u[j] = *reinterpret_cast<uint*>(&h);
  }
  uint4* o = (uint4*)dst;
  o[0] = make_uint4(u[0], u[1], u[2], u[3]);
  o[1] = make_uint4(u[4], u[5], u[6], u[7]);
}

// fp16 gather: 16 lanes x 8B = 128B row; lane col covers cols 4c..4c+3
#define AGG_BODY16(TABLE, WEXPR0, WEXPR1, WEXPR2, WEXPR3)                        \
  float4 acc0 = make_float4(0.f, 0.f, 0.f, 0.f);                                 \
  float4 acc1 = make_float4(0.f, 0.f, 0.f, 0.f);                                 \
  float4 acc2 = make_float4(0.f, 0.f, 0.f, 0.f);                                 \
  float4 acc3 = make_float4(0.f, 0.f, 0.f, 0.f);                                 \
  int last = end - 1;                                                            \
  for (int m = start; m < end; m += 16) {                                        \
    int e0 = m + sub, e1 = e0 + 4, e2 = e0 + 8, e3 = e0 + 12;                    \
    float2 s0 = sa[min(e0, last)], s1 = sa[min(e1, last)];                       \
    float2 s2 = sa[min(e2, last)], s3 = sa[min(e3, last)];                       \
    float w0 = (e0 < end) ? (WEXPR0) : 0.f;                                      \
    float w1 = (e1 < end) ? (WEXPR1) : 0.f;                                      \
    float w2 = (e2 < end) ? (WEXPR2) : 0.f;                                      \
    float w3 = (e3 < end) ? (WEXPR3) : 0.f;                                      \
    uint2 u0 = *((const uint2*)(TABLE + (size_t)__float_as_int(s0.x) * HD) + col); \
    uint2 u1 = *((const uint2*)(TABLE + (size_t)__float_as_int(s1.x) * HD) + col); \
    uint2 u2 = *((const uint2*)(TABLE + (size_t)__float_as_int(s2.x) * HD) + col); \
    uint2 u3 = *((const uint2*)(TABLE + (size_t)__float_as_int(s3.x) * HD) + col); \
    {                                                                            \
      float2 fa = __half22float2(*reinterpret_cast<__half2*>(&u0.x));            \
      float2 fb = __half22float2(*reinterpret_cast<__half2*>(&u0.y));            \
      acc0.x = fmaf(w0, fa.x, acc0.x); acc0.y = fmaf(w0, fa.y, acc0.y);          \
      acc0.z = fmaf(w0, fb.x, acc0.z); acc0.w = fmaf(w0, fb.y, acc0.w);          \
    }                                                                            \
    {                                                                            \
      float2 fa = __half22float2(*reinterpret_cast<__half2*>(&u1.x));            \
      float2 fb = __half22float2(*reinterpret_cast<__half2*>(&u1.y));            \
      acc1.x = fmaf(w1, fa.x, acc1.x); acc1.y = fmaf(w1, fa.y, acc1.y);          \
      acc1.z = fmaf(w1, fb.x, acc1.z); acc1.w = fmaf(w1, fb.y, acc1.w);          \
    }                                                                            \
    {                                                                            \
      float2 fa = __half22float2(*reinterpret_cast<__half2*>(&u2.x));            \
      float2 fb = __half22float2(*reinterpret_cast<__half2*>(&u2.y));            \
      acc2.x = fmaf(w2, fa.x, acc2.x); acc2.y = fmaf(w2, fa.y, acc2.y);          \
      acc2.z = fmaf(w2, fb.x, acc2.z); acc2.w = fmaf(w2, fb.y, acc2.w);          \
    }                                                                            \
    {                                                                            \
      float2 fa = __half22float2(*reinterpret_cast<__half2*>(&u3.x));            \
      float2 fb = __half22float2(*reinterpret_cast<__half2*>(&u3.y));            \
      acc3.x = fmaf(w3, fa.x, acc3.x); acc3.y = fmaf(w3, fa.y, acc3.y);          \
      acc3.z = fmaf(w3, fb.x, acc3.z); acc3.w = fmaf(w3, fb.y, acc3.w);          \
    }                                                                            \
  }                                                                              \
  acc0.x = (acc0.x + acc1.x) + (acc2.x + acc3.x);                                \
  acc0.y = (acc0.y + acc1.y) + (acc2.y + acc3.y);                                \
  acc0.z = (acc0.z + acc1.z) + (acc2.z + acc3.z);                                \
  acc0.w = (acc0.w + acc1.w) + (acc2.w + acc3.w);                                \
  _Pragma("unroll")                                                              \
  for (int off = 16; off <= 32; off <<= 1) {                                     \
    acc0.x += __shfl_xor(acc0.x, off); acc0.y += __shfl_xor(acc0.y, off);        \
    acc0.z += __shfl_xor(acc0.z, off); acc0.w += __shfl_xor(acc0.w, off);        \
  }

// ---------------- kernels ----------------

// lin0: h = x@Wn + bn -> hA, LDS ; h0 = h@Wl + bl -> hB16 ; cvec/dvec dots
__global__ __launch_bounds__(256) void k_lin0(
    const float* __restrict__ x,
    const float* __restrict__ Wn, const float* __restrict__ bn,
    const float* __restrict__ Wl, const float* __restrict__ bl,
    const float* __restrict__ Wa,
    float* __restrict__ hA, __half* __restrict__ hB16,
    float* __restrict__ cvec, float* __restrict__ dvec) {
  __shared__ float sh[64 * LP];
  __shared__ float sc[4][64], sd[4][64];
  int slot = threadIdx.x & 63;
  int cc = __builtin_amdgcn_readfirstlane(threadIdx.x >> 6);
  int c0 = cc * 16;
  int n0 = blockIdx.x * 64 + slot;
  bool valid = n0 < NODES;
  int n = valid ? n0 : NODES - 1;
  const float4* xr = (const float4*)(x + (size_t)n * NFD);
  float acc[16];
#pragma unroll
  for (int j = 0; j < 16; j++) acc[j] = bn[c0 + j];
#pragma unroll
  for (int q = 0; q < 4; q++) {
    float4 xa = xr[q];
    float xs[4] = {xa.x, xa.y, xa.z, xa.w};
#pragma unroll
    for (int t = 0; t < 4; t++)
#pragma unroll
      for (int j = 0; j < 16; j++)
        acc[j] = fmaf(xs[t], Wn[(q * 4 + t) * HD + c0 + j], acc[j]);
  }
#pragma unroll
  for (int j = 0; j < 16; j++) sh[slot * LP + c0 + j] = acc[j];
  if (valid) {
    float4* o = (float4*)(hA + (size_t)n * HD + c0);
    o[0] = make_float4(acc[0], acc[1], acc[2], acc[3]);
    o[1] = make_float4(acc[4], acc[5], acc[6], acc[7]);
    o[2] = make_float4(acc[8], acc[9], acc[10], acc[11]);
    o[3] = make_float4(acc[12], acc[13], acc[14], acc[15]);
  }
  __syncthreads();
  float a2[16];
#pragma unroll
  for (int j = 0; j < 16; j++) a2[j] = bl[c0 + j];
#pragma unroll 8
  for (int k = 0; k < 64; k++) {
    float hk = sh[slot * LP + k];
#pragma unroll
    for (int j = 0; j < 16; j++)
      a2[j] = fmaf(hk, Wl[k * HD + c0 + j], a2[j]);
  }
  float cn = 0.f, dn = 0.f;
#pragma unroll
  for (int j = 0; j < 16; j++) {
    cn = fmaf(a2[j], Wa[c0 + j], cn);
    dn = fmaf(a2[j], Wa[64 + c0 + j], dn);
  }
  if (valid) store16h(hB16 + (size_t)n * HD + c0, a2);
  sc[cc][slot] = cn;
  sd[cc][slot] = dn;
  __syncthreads();
  if (cc == 0 && valid) {
    cvec[n] = sc[0][slot] + sc[1][slot] + sc[2][slot] + sc[3][slot];
    dvec[n] = sd[0][slot] + sd[1][slot] + sd[2][slot] + sd[3][slot];
  }
}

// layer0 aggregation: gather hB16, write hC (fp32) + hC16
__global__ __launch_bounds__(256) void k_agg_att(
    const float2* __restrict__ sa, const int* __restrict__ rowptr,
    const float* __restrict__ hA, const __half* __restrict__ hB16,
    const float* __restrict__ g, const float* __restrict__ bt,
    float* __restrict__ hC, __half* __restrict__ hC16) {
  int lane = threadIdx.x & 63;
  int node = __builtin_amdgcn_readfirstlane(blockIdx.x * 4 + (threadIdx.x >> 6));
  if (node >= NODES) return;
  int start = rowptr[node], end = rowptr[node + 1];
  int sub = lane >> 4, col = lane & 15;
  float4 gg = ((const float4*)g)[col];
  float4 bb = ((const float4*)bt)[col];
  float4 ha = *((const float4*)(hA + (size_t)node * HD) + col);
  AGG_BODY16(hB16, s0.y, s1.y, s2.y, s3.y)
  if (lane < 16) {
    float4 v;
    v.x = fmaxf(acc0.x * (gg.x * BN_INV) + bb.x, 0.f) + ha.x;
    v.y = fmaxf(acc0.y * (gg.y * BN_INV) + bb.y, 0.f) + ha.y;
    v.z = fmaxf(acc0.z * (gg.z * BN_INV) + bb.z, 0.f) + ha.z;
    v.w = fmaxf(acc0.w * (gg.w * BN_INV) + bb.w, 0.f) + ha.w;
    *((float4*)(hC + (size_t)node * HD) + col) = v;
    __half2 p0 = __float22half2_rn(make_float2(v.x, v.y));
    __half2 p1 = __float22half2_rn(make_float2(v.z, v.w));
    uint2 u;
    u.x = *reinterpret_cast<uint*>(&p0);
    u.y = *reinterpret_cast<uint*>(&p1);
    *((uint2*)(hC16 + (size_t)node * HD) + col) = u;
  }
}

// FUSED mean-gather (hC16) + SAGE + GCN pre-GEMM -> hA (t), hD + hD16
__global__ __launch_bounds__(256) void k_msage(
    const float2* __restrict__ sa, const int* __restrict__ rowptr,
    const float* __restrict__ hC, const __half* __restrict__ hC16,
    const float* __restrict__ Wl, const float* __restrict__ bl,
    const float* __restrict__ Wr, const float* __restrict__ Wg,
    const float* __restrict__ g, const float* __restrict__ bt,
    const float* __restrict__ dis,
    float* __restrict__ hA, float* __restrict__ hD, __half* __restrict__ hD16) {
  __shared__ float sh[64 * LP];
  int lane = threadIdx.x & 63;
  int wu = __builtin_amdgcn_readfirstlane(threadIdx.x >> 6);
  int sub = lane >> 4, col = lane & 15;
  int nbase = blockIdx.x * 64;
  // phase 1: mean-gather from fp16 table
  for (int i = 0; i < 16; i++) {
    int slot = wu * 16 + i;
    int nn = min(nbase + slot, NODES - 1);
    int start = rowptr[nn], end = rowptr[nn + 1];
    float rdeg = 1.f / fmaxf((float)(end - start), 1.f);
    AGG_BODY16(hC16, 1.f, 1.f, 1.f, 1.f)
    if (lane < 16) {
      sh[slot * LP + col * 4 + 0] = acc0.x * rdeg;
      sh[slot * LP + col * 4 + 1] = acc0.y * rdeg;
      sh[slot * LP + col * 4 + 2] = acc0.z * rdeg;
      sh[slot * LP + col * 4 + 3] = acc0.w * rdeg;
    }
  }
  __syncthreads();
  // phase 2: GEMMs
  int c0 = wu * 16;
  int n0 = nbase + lane;
  bool valid = n0 < NODES;
  int n = valid ? n0 : NODES - 1;
  const float4* cr = (const float4*)(hC + (size_t)n * HD);
  float acc[16];
#pragma unroll
  for (int j = 0; j < 16; j++) acc[j] = bl[c0 + j];
#pragma unroll 8
  for (int k = 0; k < 64; k++) {
    float mk = sh[lane * LP + k];
#pragma unroll
    for (int j = 0; j < 16; j++)
      acc[j] = fmaf(mk, Wl[k * HD + c0 + j], acc[j]);
  }
#pragma unroll 4
  for (int q = 0; q < 16; q++) {
    float4 ac = cr[q];
    float cs[4] = {ac.x, ac.y, ac.z, ac.w};
#pragma unroll
    for (int t = 0; t < 4; t++)
#pragma unroll
      for (int j = 0; j < 16; j++)
        acc[j] = fmaf(cs[t], Wr[(q * 4 + t) * HD + c0 + j], acc[j]);
  }
  float tv[16];
  {
    float4 r0 = cr[wu * 4 + 0], r1 = cr[wu * 4 + 1], r2 = cr[wu * 4 + 2], r3 = cr[wu * 4 + 3];
    float rv[16] = {r0.x, r0.y, r0.z, r0.w, r1.x, r1.y, r1.z, r1.w,
                    r2.x, r2.y, r2.z, r2.w, r3.x, r3.y, r3.z, r3.w};
#pragma unroll
    for (int j = 0; j < 16; j++)
      tv[j] = fmaxf(acc[j] * (g[c0 + j] * BN_INV) + bt[c0 + j], 0.f) + rv[j];
  }
  __syncthreads();  // mean rows fully consumed -> safe to overwrite
#pragma unroll
  for (int j = 0; j < 16; j++) sh[lane * LP + c0 + j] = tv[j];
  if (valid) {
    float4* o = (float4*)(hA + (size_t)n * HD + c0);
    o[0] = make_float4(tv[0], tv[1], tv[2], tv[3]);
    o[1] = make_float4(tv[4], tv[5], tv[6], tv[7]);
    o[2] = make_float4(tv[8], tv[9], tv[10], tv[11]);
    o[3] = make_float4(tv[12], tv[13], tv[14], tv[15]);
  }
  __syncthreads();
  float di = dis[n];
  float a2[16];
#pragma unroll
  for (int j = 0; j < 16; j++) a2[j] = 0.f;
#pragma unroll 8
  for (int k = 0; k < 64; k++) {
    float tk = sh[lane * LP + k];
#pragma unroll
    for (int j = 0; j < 16; j++)
      a2[j] = fmaf(tk, Wg[k * HD + c0 + j], a2[j]);
  }
#pragma unroll
  for (int j = 0; j < 16; j++) a2[j] *= di;
  if (valid) {
    float4* o = (float4*)(hD + (size_t)n * HD + c0);
    o[0] = make_float4(a2[0], a2[1], a2[2], a2[3]);
    o[1] = make_float4(a2[4], a2[5], a2[6], a2[7]);
    o[2] = make_float4(a2[8], a2[9], a2[10], a2[11]);
    o[3] = make_float4(a2[12], a2[13], a2[14], a2[15]);
    store16h(hD16 + (size_t)n * HD + c0, a2);
  }
}

// FUSED GCN aggregation (gather hD16) + regressor head -> out
__global__ __launch_bounds__(256) void k_gcnreg(
    const float2* __restrict__ sa, const int* __restrict__ rowptr,
    const float* __restrict__ dis,
    const float* __restrict__ hA,     // t (residual ident)
    const float* __restrict__ hD,     // fp32 self rows
    const __half* __restrict__ hD16,  // fp16 gather table
    const float* __restrict__ bg,
    const float* __restrict__ g, const float* __restrict__ bt,
    const float* __restrict__ W1, const float* __restrict__ b1,
    const float* __restrict__ W2, const float* __restrict__ b2,
    const float* __restrict__ W3, const float* __restrict__ b3,
    float* __restrict__ out) {
  __shared__ float sh[64 * LP];
  __shared__ float sred[4][64];
  int lane = threadIdx.x & 63;
  int wu = __builtin_amdgcn_readfirstlane(threadIdx.x >> 6);
  int sub = lane >> 4, col = lane & 15;
  int nbase = blockIdx.x * 64;
  float4 gg = ((const float4*)g)[col];
  float4 bb = ((const float4*)bt)[col];
  float4 bgv = ((const float4*)bg)[col];
  // phase 1: gcn-gather + epilogue -> layer2 output rows in LDS
  for (int i = 0; i < 16; i++) {
    int slot = wu * 16 + i;
    int nn = min(nbase + slot, NODES - 1);
    int start = rowptr[nn], end = rowptr[nn + 1];
    float di = dis[nn];
    float4 sv = *((const float4*)(hD + (size_t)nn * HD) + col);  // self-loop
    float4 ha = *((const float4*)(hA + (size_t)nn * HD) + col);
    AGG_BODY16(hD16, 1.f, 1.f, 1.f, 1.f)
    if (lane < 16) {
      sh[slot * LP + col * 4 + 0] =
          fmaxf((di * (acc0.x + sv.x) + bgv.x) * (gg.x * BN_INV) + bb.x, 0.f) + ha.x;
      sh[slot * LP + col * 4 + 1] =
          fmaxf((di * (acc0.y + sv.y) + bgv.y) * (gg.y * BN_INV) + bb.y, 0.f) + ha.y;
      sh[slot * LP + col * 4 + 2] =
          fmaxf((di * (acc0.z + sv.z) + bgv.z) * (gg.z * BN_INV) + bb.z, 0.f) + ha.z;
      sh[slot * LP + col * 4 + 3] =
          fmaxf((di * (acc0.w + sv.w) + bgv.w) * (gg.w * BN_INV) + bb.w, 0.f) + ha.w;
    }
  }
  __syncthreads();
  // phase 2: regressor GEMM chain from LDS
  int c0 = wu * 16;
  int n0 = nbase + lane;
  bool valid = n0 < NODES;
  int n = valid ? n0 : NODES - 1;
  float acc[16];
#pragma unroll
  for (int j = 0; j < 16; j++) acc[j] = b1[c0 + j];
#pragma unroll 8
  for (int k = 0; k < 64; k++) {
    float rk = sh[lane * LP + k];
#pragma unroll
    for (int j = 0; j < 16; j++)
      acc[j] = fmaf(rk, W1[k * HD + c0 + j], acc[j]);
  }
  float t1v[16];
#pragma unroll
  for (int j = 0; j < 16; j++) t1v[j] = fmaxf(acc[j], 0.f);
  __syncthreads();  // layer2 rows consumed -> overwrite with t1
#pragma unroll
  for (int j = 0; j < 16; j++) sh[lane * LP + c0 + j] = t1v[j];
  __syncthreads();
  int d0 = wu * 8;
  float a2[8];
#pragma unroll
  for (int j = 0; j < 8; j++) a2[j] = b2[d0 + j];
#pragma unroll 8
  for (int k = 0; k < 64; k++) {
    float tk = sh[lane * LP + k];
#pragma unroll
    for (int j = 0; j < 8; j++)
      a2[j] = fmaf(tk, W2[k * 32 + d0 + j], a2[j]);
  }
  float part = 0.f;
#pragma unroll
  for (int j = 0; j < 8; j++) part = fmaf(fmaxf(a2[j], 0.f), W3[d0 + j], part);
  sred[wu][lane] = part;
  __syncthreads();
  if (wu == 0 && valid)
    out[n] = sred[0][lane] + sred[1][lane] + sred[2][lane] + sred[3][lane] + b3[0];
}

// ---------------- host launch ----------------

extern "C" void kernel_launch(void* const* d_in, const int* in_sizes, int n_in,
                              void* d_out, int out_size, void* d_ws, size_t ws_size,
                              hipStream_t stream) {
  const float* x      = (const float*)d_in[0];
  const float* ea     = (const float*)d_in[1];
  const int*   ei     = (const int*)d_in[2];
  const float* W_node = (const float*)d_in[3];
  const float* b_node = (const float*)d_in[4];
  // d_in[5], d_in[6]: W_edge/b_edge — unused by the reference output
  const float* W_lin0 = (const float*)d_in[7];
  const float* b_lin0 = (const float*)d_in[8];
  const float* W_att0 = (const float*)d_in[9];
  const float* b_att0 = (const float*)d_in[10];
  const float* W_sl   = (const float*)d_in[11];
  const float* b_sl   = (const float*)d_in[12];
  const float* W_sr   = (const float*)d_in[13];
  const float* W_gcn  = (const float*)d_in[14];
  const float* b_gcn  = (const float*)d_in[15];
  const float* bn_g   = (const float*)d_in[16];  // [3,64]
  const float* bn_b   = (const float*)d_in[17];
  const float* W_r1   = (const float*)d_in[18];
  const float* b_r1   = (const float*)d_in[19];
  const float* W_r2   = (const float*)d_in[20];
  const float* b_r2   = (const float*)d_in[21];
  const float* W_r3   = (const float*)d_in[22];
  const float* b_r3   = (const float*)d_in[23];
  float* out = (float*)d_out;

  char* ws = (char*)d_ws;
  size_t o = 0;
  auto alloc = [&](size_t bytes) -> void* {
    void* p = ws + o;
    o += (bytes + 255) & ~(size_t)255;
    return p;
  };
  int*    deg    = (int*)alloc(NODES * 4);
  int*    rowptr = (int*)alloc((NODES + 1) * 4);
  int*    cur    = (int*)alloc(NODES * 4);
  int*    part   = (int*)alloc(256 * 4);
  float2* sa     = (float2*)alloc((size_t)EDGES * 8);
  float*  hA     = (float*)alloc((size_t)NODES * HD * 4);
  float*  hC     = (float*)alloc((size_t)NODES * HD * 4);
  float*  hD     = (float*)alloc((size_t)NODES * HD * 4);
  __half* hB16   = (__half*)alloc((size_t)NODES * HD * 2);
  __half* hC16   = (__half*)alloc((size_t)NODES * HD * 2);
  __half* hD16   = (__half*)alloc((size_t)NODES * HD * 2);
  float*  cvec   = (float*)alloc(NODES * 4);
  float*  dvec   = (float*)alloc(NODES * 4);
  float*  dis    = (float*)alloc(NODES * 4);
  (void)ws_size; (void)in_sizes; (void)n_in; (void)out_size;

  const int EB  = (EDGES + 255) / 256;
  const int NT  = (NODES + 63) / 64;     // 64 nodes/block, 256 threads
  const int NBW = (NODES + 3) / 4;       // wave-per-node (4 waves/block)

  hipMemsetAsync(deg, 0, NODES * 4, stream);
  k_hist<<<EB, 256, 0, stream>>>(ei, deg);
  k_scan1<<<NCHUNK, 256, 0, stream>>>(deg, part);
  k_scan2<<<1, 64, 0, stream>>>(part);
  k_scan3<<<NCHUNK, 256, 0, stream>>>(deg, part, rowptr, cur, dis);

  k_lin0<<<NT, 256, 0, stream>>>(x, W_node, b_node, W_lin0, b_lin0, W_att0,
                                 hA, hB16, cvec, dvec);
  k_fillatt<<<EB, 256, 0, stream>>>(ei, ea, cvec, dvec, W_att0, b_att0, cur, sa);
  k_agg_att<<<NBW, 256, 0, stream>>>(sa, rowptr, hA, hB16,
                                     bn_g + 0 * HD, bn_b + 0 * HD, hC, hC16);
  // fused mean-gather + SAGE + GCN pre-GEMM: t -> hA, hBp -> hD/hD16
  k_msage<<<NT, 256, 0, stream>>>(sa, rowptr, hC, hC16, W_sl, b_sl, W_sr, W_gcn,
                                  bn_g + 1 * HD, bn_b + 1 * HD, dis, hA, hD, hD16);
  // fused GCN aggregation + regressor -> out
  k_gcnreg<<<NT, 256, 0, stream>>>(sa, rowptr, dis, hA, hD, hD16, b_gcn,
                                   bn_g + 2 * HD, bn_b + 2 * HD,
                                   W_r1, b_r1, W_r2, b_r2, W_r3, b_r3, out);
}